// Round 5
// baseline (223.744 us; speedup 1.0000x reference)
//
#include <hip/hip_runtime.h>
#include <math.h>

#define HW 512
#define NIMG 24              // 8*3 images per tensor
#define NB 362               // radial bins
#define PLANE (HW*HW)
#define NC 257               // stored spectral columns (0..256), Hermitian half
#define CP (NC*HW)           // 131584 floats per component per image
#define NG 65                // col-groups per image (4 cols each, last ragged)
#define NPB (NIMG*NG)        // 1560 partial-bin blocks

// ws layout (float units):
#define OFF_PM  0                          // [NPB*NB] partial mag sums
#define OFF_PD  (NPB*NB)                   // [NPB*NB] partial d sums  (=564720)
#define OFF_CNT (2*NPB*NB)                 // [NB] int counts          (=1129440)
#define OFF_PR  1129808                    // P real, col-major [img][col][row], 16-aligned
#define OFF_PIm (OFF_PR + NIMG*CP)         // P imag
#define OFF_TR  (OFF_PR + 2*NIMG*CP)       // T real
#define OFF_TI  (OFF_PR + 3*NIMG*CP)       // T imag
// total ~52.5 MiB

// Exact floor of shifted radius (integer-exact; validated R1-R4).
__device__ __forceinline__ int rbin(int ky, int kx) {
    int sy = (ky + 256) & 511;
    int sx = (kx + 256) & 511;
    int py = 2*sy - 511;
    int px = 2*sx - 511;
    int m2 = py*py + px*px;
    int k = (int)(0.5f * sqrtf((float)m2));
    if ((2*(k+1))*(2*(k+1)) <= m2) ++k;
    if (k > 0 && (2*k)*(2*k) > m2) --k;
    return k;
}

__device__ __forceinline__ void cmul(float& xr, float& xi, float wr, float wi) {
    float r = xr*wr - xi*wi;
    xi = xr*wi + xi*wr;
    xr = r;
}

// 8-point DFT in registers, natural order (validated R2-R4).
__device__ __forceinline__ void dft8(float ar[8], float ai[8]) {
    const float C = 0.70710678118654752440f;
    float t0r=ar[0]+ar[4], t0i=ai[0]+ai[4];
    float t1r=ar[0]-ar[4], t1i=ai[0]-ai[4];
    float t2r=ar[2]+ar[6], t2i=ai[2]+ai[6];
    float t3r=ar[2]-ar[6], t3i=ai[2]-ai[6];
    float E0r=t0r+t2r, E0i=t0i+t2i;
    float E2r=t0r-t2r, E2i=t0i-t2i;
    float E1r=t1r+t3i, E1i=t1i-t3r;
    float E3r=t1r-t3i, E3i=t1i+t3r;
    float u0r=ar[1]+ar[5], u0i=ai[1]+ai[5];
    float u1r=ar[1]-ar[5], u1i=ai[1]-ai[5];
    float u2r=ar[3]+ar[7], u2i=ai[3]+ai[7];
    float u3r=ar[3]-ar[7], u3i=ai[3]-ai[7];
    float O0r=u0r+u2r, O0i=u0i+u2i;
    float O2r=u0r-u2r, O2i=u0i-u2i;
    float O1r=u1r+u3i, O1i=u1i-u3r;
    float O3r=u1r-u3i, O3i=u1i+u3r;
    float W1r = C*(O1r+O1i), W1i = C*(O1i-O1r);
    float W2r = O2i,         W2i = -O2r;
    float W3r = C*(O3i-O3r), W3i = -C*(O3r+O3i);
    ar[0]=E0r+O0r; ai[0]=E0i+O0i;
    ar[4]=E0r-O0r; ai[4]=E0i-O0i;
    ar[1]=E1r+W1r; ai[1]=E1i+W1i;
    ar[5]=E1r-W1r; ai[5]=E1i-W1i;
    ar[2]=E2r+W2r; ai[2]=E2i+W2i;
    ar[6]=E2r-W2r; ai[6]=E2i-W2i;
    ar[3]=E3r+W3r; ai[3]=E3i+W3i;
    ar[7]=E3r-W3r; ai[7]=E3i-W3i;
}

__device__ __forceinline__ void twiddle7(float ar[8], float ai[8], float wr, float wi) {
    float pr = wr, pi = wi;
    cmul(ar[1], ai[1], pr, pi);
    #pragma unroll
    for (int k = 2; k < 8; ++k) {
        float nr = pr*wr - pi*wi;
        pi = pr*wi + pi*wr;
        pr = nr;
        cmul(ar[k], ai[k], pr, pi);
    }
}

// 512-pt FFT, one wave per line, per-wave scratch (Lr/Li 544 floats each).
// In:  ar[j] = x[64*j + lane];  Out: ar[d] = X[(lane>>3) + 8*(lane&7) + 64*d]
// Only wave-level barriers inside — safe under divergent (per-wave) execution.
__device__ __forceinline__ void fft512r(float ar[8], float ai[8],
                                        float* Lr, float* Li, int lane) {
    float s, c;
    dft8(ar, ai);
    __sincosf((float)lane * (-6.28318530717958647692f/512.0f), &s, &c);
    twiddle7(ar, ai, c, s);
    __builtin_amdgcn_wave_barrier();
    #pragma unroll
    for (int j = 0; j < 8; ++j) { Lr[j*68+lane] = ar[j]; Li[j*68+lane] = ai[j]; }
    __builtin_amdgcn_wave_barrier();
    int k1 = lane >> 3, b = lane & 7;
    #pragma unroll
    for (int a = 0; a < 8; ++a) { ar[a] = Lr[k1*68+8*a+b]; ai[a] = Li[k1*68+8*a+b]; }
    dft8(ar, ai);
    __sincosf((float)b * (-6.28318530717958647692f/64.0f), &s, &c);
    twiddle7(ar, ai, c, s);
    __builtin_amdgcn_wave_barrier();
    #pragma unroll
    for (int cc = 0; cc < 8; ++cc) {
        int ad = k1*68 + 8*cc + ((b + cc) & 7);
        Lr[ad] = ar[cc]; Li[ad] = ai[cc];
    }
    __builtin_amdgcn_wave_barrier();
    #pragma unroll
    for (int bb = 0; bb < 8; ++bb) {
        int ad = k1*68 + 8*b + ((bb + b) & 7);
        ar[bb] = Lr[ad]; ai[bb] = Li[ad];
    }
    __builtin_amdgcn_wave_barrier();
    dft8(ar, ai);
}

// Bin populations (mirrors np.bincount of r_int).
__global__ __launch_bounds__(256) void k_counts(int* __restrict__ counts) {
    __shared__ int cb[NB];
    int t = threadIdx.x;
    for (int j = t; j < NB; j += 256) cb[j] = 0;
    __syncthreads();
    int base = blockIdx.x * 4096;
    #pragma unroll
    for (int j = 0; j < 16; ++j) {
        int idx = base + t + j*256;
        atomicAdd(&cb[rbin(idx >> 9, idx & 511)], 1);
    }
    __syncthreads();
    for (int j = t; j < NB; j += 256) atomicAdd(&counts[j], cb[j]);
}

// Row stage: pack pred-row (re) + tgt-row (im) into ONE complex FFT, unpack
// Hermitian halves, store cols 0..256 of P and T spectra col-major.
// Block = 4 waves = 4 rows of one image. 24*128 = 3072 blocks.
__global__ __launch_bounds__(256) void k_rowfft(const float* __restrict__ pred,
                                                const float* __restrict__ tgt,
                                                float* __restrict__ ws) {
    __shared__ float smem[4352];           // 4 x 1088 per-wave scratch; tiles alias
    int t = threadIdx.x, lane = t & 63, w = t >> 6;
    int b = blockIdx.x;
    int img = b >> 7;
    int r0 = (b & 127) << 2;
    int r = r0 + w;
    const float* pr = pred + (size_t)img*PLANE + (size_t)r*HW;
    const float* tr = tgt  + (size_t)img*PLANE + (size_t)r*HW;
    float ar[8], ai[8];
    #pragma unroll
    for (int j = 0; j < 8; ++j) { ar[j] = pr[64*j + lane]; ai[j] = tr[64*j + lane]; }
    float* Lr = smem + w*1088;
    float* Li = Lr + 544;
    fft512r(ar, ai, Lr, Li, lane);
    __builtin_amdgcn_wave_barrier();
    // stash Z in natural order in own scratch
    #pragma unroll
    for (int d = 0; d < 8; ++d) {
        int k = (lane >> 3) + ((lane & 7) << 3) + (d << 6);
        Lr[k] = ar[d]; Li[k] = ai[d];
    }
    __builtin_amdgcn_wave_barrier();
    // unpack to regs: P[k]=(Z[k]+conj(Z[-k]))/2, T[k]=-i(Z[k]-conj(Z[-k]))/2
    float Pr4[4], Pi4[4], Tr4[4], Ti4[4], P256 = 0.f, T256 = 0.f;
    #pragma unroll
    for (int m = 0; m < 4; ++m) {
        int kk = 64*m + lane;
        int j2 = (512 - kk) & 511;
        float z1r = Lr[kk], z1i = Li[kk];
        float z2r = Lr[j2], z2i = Li[j2];
        Pr4[m] = 0.5f*(z1r + z2r); Pi4[m] = 0.5f*(z1i - z2i);
        Tr4[m] = 0.5f*(z1i + z2i); Ti4[m] = 0.5f*(z2r - z1r);
    }
    if (lane == 0) { P256 = Lr[256]; T256 = Li[256]; }
    // tiles alias scratch: TA/TB = [257 cols][stride 5] (gcd(5,32)=1: conflict-free)
    float* TA = smem;
    float* TB = smem + 1285;

    // ---- P tiles + store ----
    __syncthreads();                       // all unpack reads done
    #pragma unroll
    for (int m = 0; m < 4; ++m) {
        int kk = 64*m + lane;
        TA[kk*5 + w] = Pr4[m];
        TB[kk*5 + w] = Pi4[m];
    }
    if (lane == 0) { TA[256*5 + w] = P256; TB[256*5 + w] = 0.f; }
    __syncthreads();
    for (int idx = t; idx < 2*NC; idx += 256) {
        int comp = (idx >= NC);
        int col = idx - comp*NC;
        const float* Tt = comp ? TB : TA;
        float* outP = ws + (size_t)(comp ? OFF_PIm : OFF_PR)
                      + (size_t)img*CP + (size_t)col*HW + r0;
        *(float4*)outP = make_float4(Tt[col*5], Tt[col*5+1], Tt[col*5+2], Tt[col*5+3]);
    }

    // ---- T tiles + store ----
    __syncthreads();                       // P tile reads done
    #pragma unroll
    for (int m = 0; m < 4; ++m) {
        int kk = 64*m + lane;
        TA[kk*5 + w] = Tr4[m];
        TB[kk*5 + w] = Ti4[m];
    }
    if (lane == 0) { TA[256*5 + w] = T256; TB[256*5 + w] = 0.f; }
    __syncthreads();
    for (int idx = t; idx < 2*NC; idx += 256) {
        int comp = (idx >= NC);
        int col = idx - comp*NC;
        const float* Tt = comp ? TB : TA;
        float* outP = ws + (size_t)(comp ? OFF_TI : OFF_TR)
                      + (size_t)img*CP + (size_t)col*HW + r0;
        *(float4*)outP = make_float4(Tt[col*5], Tt[col*5+1], Tt[col*5+2], Tt[col*5+3]);
    }
}

// Col stage: FFT columns 0..256 of P and T; per-pixel quantities are
// conj-invariant so each pixel of col kx (1..255) also bins into the mirror
// bin of col 512-kx. Block = 4 waves = 4 cols. Per-block partial bin sums.
__global__ __launch_bounds__(256) void k_colfft(const float* __restrict__ ws,
                                                float* __restrict__ gPM,
                                                float* __restrict__ gPD) {
    __shared__ float smem[4352];
    __shared__ float binM[NB], binD[NB];
    int t = threadIdx.x, lane = t & 63, w = t >> 6;
    for (int j = t; j < NB; j += 256) { binM[j] = 0.f; binD[j] = 0.f; }
    __syncthreads();
    int b = blockIdx.x;                    // NPB
    int img = b / NG;
    int g = b - img*NG;
    int c = 4*g + w;
    if (c < NC) {
        float* Lr = smem + w*1088;
        float* Li = Lr + 544;
        float ar[8], ai[8], Prr[8], Pri[8];
        {
            const float* cR = ws + OFF_PR  + (size_t)img*CP + (size_t)c*HW;
            const float* cI = ws + OFF_PIm + (size_t)img*CP + (size_t)c*HW;
            #pragma unroll
            for (int j = 0; j < 8; ++j) { ar[j] = cR[64*j+lane]; ai[j] = cI[64*j+lane]; }
        }
        fft512r(ar, ai, Lr, Li, lane);
        #pragma unroll
        for (int d = 0; d < 8; ++d) { Prr[d] = ar[d]; Pri[d] = ai[d]; }
        {
            const float* cR = ws + OFF_TR + (size_t)img*CP + (size_t)c*HW;
            const float* cI = ws + OFF_TI + (size_t)img*CP + (size_t)c*HW;
            #pragma unroll
            for (int j = 0; j < 8; ++j) { ar[j] = cR[64*j+lane]; ai[j] = cI[64*j+lane]; }
        }
        fft512r(ar, ai, Lr, Li, lane);

        bool mir = (c != 0) && (c != 256);
        #pragma unroll
        for (int d = 0; d < 8; ++d) {
            int ky = (lane >> 3) + ((lane & 7) << 3) + (d << 6);
            float sp  = Prr[d]*Prr[d] + Pri[d]*Pri[d];
            float st_ = ar[d]*ar[d] + ai[d]*ai[d];
            float diff = sp - st_;
            float d2 = diff*diff;
            float er = Prr[d] + 1e-8f;
            float mag = 10.0f * __logf(er*er + Pri[d]*Pri[d]);
            int ri = rbin(ky, c);
            atomicAdd(&binM[ri], mag);
            atomicAdd(&binD[ri], d2);
            if (mir) {
                int ri2 = rbin((512 - ky) & 511, 512 - c);
                atomicAdd(&binM[ri2], mag);
                atomicAdd(&binD[ri2], d2);
            }
        }
    }
    __syncthreads();
    for (int j = t; j < NB; j += 256) {
        gPM[(size_t)b*NB + j] = binM[j];
        gPD[(size_t)b*NB + j] = binD[j];
    }
}

// Per-image: reduce partials -> bin means -> NaN-propagating min/max ->
// weights -> weighted sum -> atomic into d_out. (Numerics validated R1-R4.)
__global__ __launch_bounds__(512) void k_final(const float* __restrict__ gPM,
                                               const float* __restrict__ gPD,
                                               const int* __restrict__ counts,
                                               float* __restrict__ out) {
    __shared__ float meanb[NB];
    __shared__ float dsum[NB];
    __shared__ float rmin[512], rmax[512];
    __shared__ double sred[512];
    int t = threadIdx.x, img = blockIdx.x;
    for (int j = t; j < NB; j += 512) {
        float sm = 0.f, sd = 0.f;
        for (int g = 0; g < NG; ++g) {
            sm += gPM[(size_t)(img*NG + g)*NB + j];
            sd += gPD[(size_t)(img*NG + g)*NB + j];
        }
        meanb[j] = sm / (float)counts[j];
        dsum[j] = sd;
    }
    __syncthreads();
    float vmin = INFINITY, vmax = -INFINITY;
    if (t >= 1 && t <= 360) { vmin = meanb[t]; vmax = meanb[t]; }
    rmin[t] = vmin; rmax[t] = vmax;
    __syncthreads();
    for (int s = 256; s > 0; s >>= 1) {
        if (t < s) {
            float a = rmin[t], bb = rmin[t+s];
            rmin[t] = (a != a || bb != bb) ? __int_as_float(0x7fc00000) : fminf(a, bb);
            a = rmax[t]; bb = rmax[t+s];
            rmax[t] = (a != a || bb != bb) ? __int_as_float(0x7fc00000) : fmaxf(a, bb);
        }
        __syncthreads();
    }
    float pmin = rmin[0], pmax = rmax[0];
    double part = 0.0;
    for (int k = t; k < NB; k += 512) {
        float wgt;
        if (k == NB - 1) {
            wgt = 1.0f;
        } else {
            int idx = (k == 0) ? 1 : k;
            float e = (meanb[idx] - pmin) / (pmax - pmin);
            float wv = 1.0f - e;
            if (wv != wv) wv = 0.0f;
            wv = fminf(fmaxf(wv, 0.0f), 1.0f);
            wgt = wv;
        }
        part += (double)wgt * (double)dsum[k];
    }
    sred[t] = part;
    __syncthreads();
    for (int s = 256; s > 0; s >>= 1) {
        if (t < s) sred[t] += sred[t+s];
        __syncthreads();
    }
    if (t == 0) atomicAdd(out, (float)(sred[0] / 6291456.0));
}

extern "C" void kernel_launch(void* const* d_in, const int* in_sizes, int n_in,
                              void* d_out, int out_size, void* d_ws, size_t ws_size,
                              hipStream_t stream) {
    const float* pred = (const float*)d_in[0];
    const float* tgt  = (const float*)d_in[1];
    float* ws = (float*)d_ws;
    hipMemsetAsync((char*)d_ws + (size_t)OFF_CNT*4, 0, NB*4, stream);
    hipMemsetAsync(d_out, 0, sizeof(float), stream);
    k_counts<<<64, 256, 0, stream>>>((int*)(ws + OFF_CNT));
    k_rowfft<<<NIMG*128, 256, 0, stream>>>(pred, tgt, ws);
    k_colfft<<<NPB, 256, 0, stream>>>(ws, ws + OFF_PM, ws + OFF_PD);
    k_final<<<NIMG, 512, 0, stream>>>(ws + OFF_PM, ws + OFF_PD,
                                      (const int*)(ws + OFF_CNT), (float*)d_out);
}

// Round 6
// 178.983 us; speedup vs baseline: 1.2501x; 1.2501x over previous
//
#include <hip/hip_runtime.h>
#include <math.h>

#define HW 512
#define NIMG 24              // 8*3 images per tensor
#define NB 362               // radial bins
#define PLANE (HW*HW)
#define NC 257               // stored spectral columns (0..256), Hermitian half
#define CP (NC*HW)           // 131584 floats per component per image
#define NG 65                // col-groups per image (4 cols each, last ragged)
#define NPB (NIMG*NG)        // 1560 partial-bin blocks

// ws layout (float units):
#define OFF_PM  0                          // [NPB*NB] partial mag sums
#define OFF_PD  (NPB*NB)                   // [NPB*NB] partial d sums
#define OFF_CNT (2*NPB*NB)                 // [NB] int counts
#define OFF_PR  1129808                    // P real, col-major [img][col][row]
#define OFF_PIm (OFF_PR + NIMG*CP)         // P imag
#define OFF_TR  (OFF_PR + 2*NIMG*CP)       // T real
#define OFF_TI  (OFF_PR + 3*NIMG*CP)       // T imag

// Exact bin for ODD integer u,v (as floats): m2 = u^2+v^2 == 2 mod 8 is never
// a perfect even square, boundary gap >= 1/(4k) ~ 6.9e-4 >> 1ulp sqrt err.
__device__ __forceinline__ int rbin_odd(float u, float v) {
    return (int)(sqrtf(fmaf(u, u, v*v)) * 0.5f);
}

__device__ __forceinline__ void cmul(float& xr, float& xi, float wr, float wi) {
    float r = xr*wr - xi*wi;
    xi = xr*wi + xi*wr;
    xr = r;
}

// 8-point DFT in registers, natural order (validated R2-R5).
__device__ __forceinline__ void dft8(float ar[8], float ai[8]) {
    const float C = 0.70710678118654752440f;
    float t0r=ar[0]+ar[4], t0i=ai[0]+ai[4];
    float t1r=ar[0]-ar[4], t1i=ai[0]-ai[4];
    float t2r=ar[2]+ar[6], t2i=ai[2]+ai[6];
    float t3r=ar[2]-ar[6], t3i=ai[2]-ai[6];
    float E0r=t0r+t2r, E0i=t0i+t2i;
    float E2r=t0r-t2r, E2i=t0i-t2i;
    float E1r=t1r+t3i, E1i=t1i-t3r;
    float E3r=t1r-t3i, E3i=t1i+t3r;
    float u0r=ar[1]+ar[5], u0i=ai[1]+ai[5];
    float u1r=ar[1]-ar[5], u1i=ai[1]-ai[5];
    float u2r=ar[3]+ar[7], u2i=ai[3]+ai[7];
    float u3r=ar[3]-ar[7], u3i=ai[3]-ai[7];
    float O0r=u0r+u2r, O0i=u0i+u2i;
    float O2r=u0r-u2r, O2i=u0i-u2i;
    float O1r=u1r+u3i, O1i=u1i-u3r;
    float O3r=u1r-u3i, O3i=u1i+u3r;
    float W1r = C*(O1r+O1i), W1i = C*(O1i-O1r);
    float W2r = O2i,         W2i = -O2r;
    float W3r = C*(O3i-O3r), W3i = -C*(O3r+O3i);
    ar[0]=E0r+O0r; ai[0]=E0i+O0i;
    ar[4]=E0r-O0r; ai[4]=E0i-O0i;
    ar[1]=E1r+W1r; ai[1]=E1i+W1i;
    ar[5]=E1r-W1r; ai[5]=E1i-W1i;
    ar[2]=E2r+W2r; ai[2]=E2i+W2i;
    ar[6]=E2r-W2r; ai[6]=E2i-W2i;
    ar[3]=E3r+W3r; ai[3]=E3i+W3i;
    ar[7]=E3r-W3r; ai[7]=E3i-W3i;
}

__device__ __forceinline__ void twiddle7(float ar[8], float ai[8], float wr, float wi) {
    float pr = wr, pi = wi;
    cmul(ar[1], ai[1], pr, pi);
    #pragma unroll
    for (int k = 2; k < 8; ++k) {
        float nr = pr*wr - pi*wi;
        pi = pr*wi + pi*wr;
        pr = nr;
        cmul(ar[k], ai[k], pr, pi);
    }
}

// 512-pt FFT, one wave per line, per-wave scratch (Lr/Li 544 floats each).
// In:  ar[j] = x[64*j + lane];  Out: ar[d] = X[(lane>>3) + 8*(lane&7) + 64*d]
__device__ __forceinline__ void fft512r(float ar[8], float ai[8],
                                        float* Lr, float* Li, int lane) {
    float s, c;
    dft8(ar, ai);
    __sincosf((float)lane * (-6.28318530717958647692f/512.0f), &s, &c);
    twiddle7(ar, ai, c, s);
    __builtin_amdgcn_wave_barrier();
    #pragma unroll
    for (int j = 0; j < 8; ++j) { Lr[j*68+lane] = ar[j]; Li[j*68+lane] = ai[j]; }
    __builtin_amdgcn_wave_barrier();
    int k1 = lane >> 3, b = lane & 7;
    #pragma unroll
    for (int a = 0; a < 8; ++a) { ar[a] = Lr[k1*68+8*a+b]; ai[a] = Li[k1*68+8*a+b]; }
    dft8(ar, ai);
    __sincosf((float)b * (-6.28318530717958647692f/64.0f), &s, &c);
    twiddle7(ar, ai, c, s);
    __builtin_amdgcn_wave_barrier();
    #pragma unroll
    for (int cc = 0; cc < 8; ++cc) {
        int ad = k1*68 + 8*cc + ((b + cc) & 7);
        Lr[ad] = ar[cc]; Li[ad] = ai[cc];
    }
    __builtin_amdgcn_wave_barrier();
    #pragma unroll
    for (int bb = 0; bb < 8; ++bb) {
        int ad = k1*68 + 8*b + ((bb + b) & 7);
        ar[bb] = Lr[ad]; ai[bb] = Li[ad];
    }
    __builtin_amdgcn_wave_barrier();
    dft8(ar, ai);
}

// Bin populations (mirrors np.bincount of r_int).
__global__ __launch_bounds__(256) void k_counts(int* __restrict__ counts) {
    __shared__ int cb[NB];
    int t = threadIdx.x;
    for (int j = t; j < NB; j += 256) cb[j] = 0;
    __syncthreads();
    int base = blockIdx.x * 4096;
    #pragma unroll
    for (int j = 0; j < 16; ++j) {
        int idx = base + t + j*256;
        float u = fabsf(2.0f*(float)(idx >> 9)  - 511.0f);
        float v = fabsf(2.0f*(float)(idx & 511) - 511.0f);
        atomicAdd(&cb[rbin_odd(u, v)], 1);
    }
    __syncthreads();
    for (int j = t; j < NB; j += 256) atomicAdd(&counts[j], cb[j]);
}

// Row stage: pack pred-row (re) + tgt-row (im) into one complex FFT; unpack
// Hermitian halves; store cols 0..256 of P and T spectra col-major.
// Block = 4 waves x 2 rows each = 8 rows. 24*64 = 1536 blocks.
__global__ __launch_bounds__(256) void k_rowfft(const float* __restrict__ pred,
                                                const float* __restrict__ tgt,
                                                float* __restrict__ ws) {
    __shared__ float smem[4672];           // 4x1088 scratch; [257][9] tiles alias
    int t = threadIdx.x, lane = t & 63, w = t >> 6;
    int b = blockIdx.x;
    int img = b >> 6;
    int r0 = (b & 63) << 3;
    int rA = r0 + 2*w;
    const float* pA = pred + (size_t)img*PLANE + (size_t)rA*HW;
    const float* tA = tgt  + (size_t)img*PLANE + (size_t)rA*HW;
    float arA[8], aiA[8], arB[8], aiB[8];
    #pragma unroll
    for (int j = 0; j < 8; ++j) {          // all 32 loads in flight
        arA[j] = pA[64*j + lane];      aiA[j] = tA[64*j + lane];
        arB[j] = pA[HW + 64*j + lane]; aiB[j] = tA[HW + 64*j + lane];
    }
    float* Lr = smem + w*1088;
    float* Li = Lr + 544;
    float PrA[4], PiA[4], TrA[4], TiA[4], P256A=0.f, T256A=0.f;
    float PrB[4], PiB[4], TrB[4], TiB[4], P256B=0.f, T256B=0.f;
    // ---- row A ----
    fft512r(arA, aiA, Lr, Li, lane);
    __builtin_amdgcn_wave_barrier();
    #pragma unroll
    for (int d = 0; d < 8; ++d) {
        int k = (lane>>3) + ((lane&7)<<3) + (d<<6);
        Lr[k] = arA[d]; Li[k] = aiA[d];
    }
    __builtin_amdgcn_wave_barrier();
    #pragma unroll
    for (int m = 0; m < 4; ++m) {
        int kk = 64*m + lane, j2 = (512 - kk) & 511;
        float z1r = Lr[kk], z1i = Li[kk], z2r = Lr[j2], z2i = Li[j2];
        PrA[m] = 0.5f*(z1r+z2r); PiA[m] = 0.5f*(z1i-z2i);
        TrA[m] = 0.5f*(z1i+z2i); TiA[m] = 0.5f*(z2r-z1r);
    }
    if (lane == 0) { P256A = Lr[256]; T256A = Li[256]; }
    __builtin_amdgcn_wave_barrier();
    // ---- row B ----
    fft512r(arB, aiB, Lr, Li, lane);
    __builtin_amdgcn_wave_barrier();
    #pragma unroll
    for (int d = 0; d < 8; ++d) {
        int k = (lane>>3) + ((lane&7)<<3) + (d<<6);
        Lr[k] = arB[d]; Li[k] = aiB[d];
    }
    __builtin_amdgcn_wave_barrier();
    #pragma unroll
    for (int m = 0; m < 4; ++m) {
        int kk = 64*m + lane, j2 = (512 - kk) & 511;
        float z1r = Lr[kk], z1i = Li[kk], z2r = Lr[j2], z2i = Li[j2];
        PrB[m] = 0.5f*(z1r+z2r); PiB[m] = 0.5f*(z1i-z2i);
        TrB[m] = 0.5f*(z1i+z2i); TiB[m] = 0.5f*(z2r-z1r);
    }
    if (lane == 0) { P256B = Lr[256]; T256B = Li[256]; }

    float* TAt = smem;                     // [257][9]
    float* TBt = smem + 2336;
    // ---- P planes ----
    __syncthreads();
    #pragma unroll
    for (int m = 0; m < 4; ++m) {
        int kk = 64*m + lane;
        TAt[kk*9 + 2*w]   = PrA[m]; TAt[kk*9 + 2*w+1] = PrB[m];
        TBt[kk*9 + 2*w]   = PiA[m]; TBt[kk*9 + 2*w+1] = PiB[m];
    }
    if (lane == 0) {
        TAt[256*9 + 2*w] = P256A; TAt[256*9 + 2*w+1] = P256B;
        TBt[256*9 + 2*w] = 0.f;   TBt[256*9 + 2*w+1] = 0.f;
    }
    __syncthreads();
    for (int idx = t; idx < 2*NC; idx += 256) {
        int comp = (idx >= NC);
        int col = idx - comp*NC;
        const float* Tt = comp ? TBt : TAt;
        float* outP = ws + (size_t)(comp ? OFF_PIm : OFF_PR)
                      + (size_t)img*CP + (size_t)col*HW + r0;
        *(float4*)outP       = make_float4(Tt[col*9],   Tt[col*9+1], Tt[col*9+2], Tt[col*9+3]);
        *(float4*)(outP + 4) = make_float4(Tt[col*9+4], Tt[col*9+5], Tt[col*9+6], Tt[col*9+7]);
    }
    // ---- T planes ----
    __syncthreads();
    #pragma unroll
    for (int m = 0; m < 4; ++m) {
        int kk = 64*m + lane;
        TAt[kk*9 + 2*w]   = TrA[m]; TAt[kk*9 + 2*w+1] = TrB[m];
        TBt[kk*9 + 2*w]   = TiA[m]; TBt[kk*9 + 2*w+1] = TiB[m];
    }
    if (lane == 0) {
        TAt[256*9 + 2*w] = T256A; TAt[256*9 + 2*w+1] = T256B;
        TBt[256*9 + 2*w] = 0.f;   TBt[256*9 + 2*w+1] = 0.f;
    }
    __syncthreads();
    for (int idx = t; idx < 2*NC; idx += 256) {
        int comp = (idx >= NC);
        int col = idx - comp*NC;
        const float* Tt = comp ? TBt : TAt;
        float* outP = ws + (size_t)(comp ? OFF_TI : OFF_TR)
                      + (size_t)img*CP + (size_t)col*HW + r0;
        *(float4*)outP       = make_float4(Tt[col*9],   Tt[col*9+1], Tt[col*9+2], Tt[col*9+3]);
        *(float4*)(outP + 4) = make_float4(Tt[col*9+4], Tt[col*9+5], Tt[col*9+6], Tt[col*9+7]);
    }
}

// Col stage: FFT cols 0..256 of P and T; stash per-pixel (mag,d2) in scratch;
// bin PAIRS (ky, 511-ky share a bin) for the column and its x-mirror.
__global__ __launch_bounds__(256) void k_colfft(const float* __restrict__ ws,
                                                float* __restrict__ gPM,
                                                float* __restrict__ gPD) {
    __shared__ float smem[4352];
    __shared__ float binM[NB], binD[NB];
    int t = threadIdx.x, lane = t & 63, w = t >> 6;
    for (int j = t; j < NB; j += 256) { binM[j] = 0.f; binD[j] = 0.f; }
    __syncthreads();
    int b = blockIdx.x;
    int img = b / NG;
    int g = b - img*NG;
    int c = 4*g + w;
    if (c < NC) {
        float* Lr = smem + w*1088;
        float* Li = Lr + 544;
        float prm[8], pim[8], trm[8], tim[8];
        const float* cPR = ws + OFF_PR  + (size_t)img*CP + (size_t)c*HW;
        const float* cPI = ws + OFF_PIm + (size_t)img*CP + (size_t)c*HW;
        const float* cTR = ws + OFF_TR  + (size_t)img*CP + (size_t)c*HW;
        const float* cTI = ws + OFF_TI  + (size_t)img*CP + (size_t)c*HW;
        #pragma unroll
        for (int j = 0; j < 8; ++j) {      // all 32 loads in flight
            prm[j] = cPR[64*j+lane]; pim[j] = cPI[64*j+lane];
            trm[j] = cTR[64*j+lane]; tim[j] = cTI[64*j+lane];
        }
        fft512r(prm, pim, Lr, Li, lane);
        __builtin_amdgcn_wave_barrier();
        fft512r(trm, tim, Lr, Li, lane);
        __builtin_amdgcn_wave_barrier();
        // per-pixel mag/d2 into scratch, indexed by true ky (conflict-free)
        #pragma unroll
        for (int d = 0; d < 8; ++d) {
            int ky = (lane>>3) + ((lane&7)<<3) + (d<<6);
            float sp  = prm[d]*prm[d] + pim[d]*pim[d];
            float st_ = trm[d]*trm[d] + tim[d]*tim[d];
            float diff = sp - st_;
            float er = prm[d] + 1e-8f;
            Lr[ky] = 10.0f * __logf(er*er + pim[d]*pim[d]);
            Li[ky] = diff*diff;
        }
        __builtin_amdgcn_wave_barrier();
        float v1 = (c == 256) ? 511.0f : (float)(2*c + 1);
        bool mir = (c >= 1 && c <= 255);
        float v2 = (float)(2*c - 1);
        #pragma unroll
        for (int p = 0; p < 4; ++p) {
            int ky = lane + 64*p;          // [0,256): pair partner is 511-ky
            float u = (float)(2*ky + 1);
            float sM = Lr[ky] + Lr[511 - ky];
            float sD = Li[ky] + Li[511 - ky];
            int k1 = rbin_odd(u, v1);
            atomicAdd(&binM[k1], sM);
            atomicAdd(&binD[k1], sD);
            if (mir) {                     // mirror col pair-sum: same LDS array
                float s2M = Lr[(512 - ky) & 511] + Lr[ky + 1];
                float s2D = Li[(512 - ky) & 511] + Li[ky + 1];
                int k2 = rbin_odd(u, v2);
                atomicAdd(&binM[k2], s2M);
                atomicAdd(&binD[k2], s2D);
            }
        }
    }
    __syncthreads();
    for (int j = t; j < NB; j += 256) {
        gPM[(size_t)b*NB + j] = binM[j];
        gPD[(size_t)b*NB + j] = binD[j];
    }
}

// Per-image: reduce partials -> bin means -> NaN-propagating min/max ->
// weights -> weighted sum -> atomic into d_out. (Numerics validated R1-R5.)
__global__ __launch_bounds__(512) void k_final(const float* __restrict__ gPM,
                                               const float* __restrict__ gPD,
                                               const int* __restrict__ counts,
                                               float* __restrict__ out) {
    __shared__ float meanb[NB];
    __shared__ float dsum[NB];
    __shared__ float rmin[512], rmax[512];
    __shared__ double sred[512];
    int t = threadIdx.x, img = blockIdx.x;
    for (int j = t; j < NB; j += 512) {
        float sm = 0.f, sd = 0.f;
        for (int g = 0; g < NG; ++g) {
            sm += gPM[(size_t)(img*NG + g)*NB + j];
            sd += gPD[(size_t)(img*NG + g)*NB + j];
        }
        meanb[j] = sm / (float)counts[j];
        dsum[j] = sd;
    }
    __syncthreads();
    float vmin = INFINITY, vmax = -INFINITY;
    if (t >= 1 && t <= 360) { vmin = meanb[t]; vmax = meanb[t]; }
    rmin[t] = vmin; rmax[t] = vmax;
    __syncthreads();
    for (int s = 256; s > 0; s >>= 1) {
        if (t < s) {
            float a = rmin[t], bb = rmin[t+s];
            rmin[t] = (a != a || bb != bb) ? __int_as_float(0x7fc00000) : fminf(a, bb);
            a = rmax[t]; bb = rmax[t+s];
            rmax[t] = (a != a || bb != bb) ? __int_as_float(0x7fc00000) : fmaxf(a, bb);
        }
        __syncthreads();
    }
    float pmin = rmin[0], pmax = rmax[0];
    double part = 0.0;
    for (int k = t; k < NB; k += 512) {
        float wgt;
        if (k == NB - 1) {
            wgt = 1.0f;
        } else {
            int idx = (k == 0) ? 1 : k;
            float e = (meanb[idx] - pmin) / (pmax - pmin);
            float wv = 1.0f - e;
            if (wv != wv) wv = 0.0f;
            wv = fminf(fmaxf(wv, 0.0f), 1.0f);
            wgt = wv;
        }
        part += (double)wgt * (double)dsum[k];
    }
    sred[t] = part;
    __syncthreads();
    for (int s = 256; s > 0; s >>= 1) {
        if (t < s) sred[t] += sred[t+s];
        __syncthreads();
    }
    if (t == 0) atomicAdd(out, (float)(sred[0] / 6291456.0));
}

extern "C" void kernel_launch(void* const* d_in, const int* in_sizes, int n_in,
                              void* d_out, int out_size, void* d_ws, size_t ws_size,
                              hipStream_t stream) {
    const float* pred = (const float*)d_in[0];
    const float* tgt  = (const float*)d_in[1];
    float* ws = (float*)d_ws;
    hipMemsetAsync((char*)d_ws + (size_t)OFF_CNT*4, 0, NB*4, stream);
    hipMemsetAsync(d_out, 0, sizeof(float), stream);
    k_counts<<<64, 256, 0, stream>>>((int*)(ws + OFF_CNT));
    k_rowfft<<<NIMG*64, 256, 0, stream>>>(pred, tgt, ws);
    k_colfft<<<NPB, 256, 0, stream>>>(ws, ws + OFF_PM, ws + OFF_PD);
    k_final<<<NIMG, 512, 0, stream>>>(ws + OFF_PM, ws + OFF_PD,
                                      (const int*)(ws + OFF_CNT), (float*)d_out);
}